// Round 9
// baseline (65.759 us; speedup 1.0000x reference)
//
#include <hip/hip_runtime.h>
#include <hip/hip_bf16.h>
#include <hip/hip_fp16.h>

typedef int   i32x4 __attribute__((ext_vector_type(4)));
typedef float f32x4 __attribute__((ext_vector_type(4)));

// Phase 1: convert h (fp32, [N,16]) -> fp16 table in workspace (32 B/row).
// 3.2 MB fits per-XCD L2 (4 MB); fp32 (6.4 MB) thrashed it (R1: 187MB L2-miss
// traffic). Plain loads/stores — nt hints regressed (R4), sc0 null (R8).
__global__ __launch_bounds__(256) void convert_h_fp16(
    const f32x4* __restrict__ h4,    // [N*4]
    uint4* __restrict__ hh,          // [N*2] uint4 (8 halfs each)
    int n_out)                       // N*2
{
    int i = blockIdx.x * blockDim.x + threadIdx.x;
    if (i >= n_out) return;
    f32x4 a = h4[2 * i];
    f32x4 b = h4[2 * i + 1];
    __half2 p[4];
    p[0] = __floats2half2_rn(a.x, a.y);
    p[1] = __floats2half2_rn(a.z, a.w);
    p[2] = __floats2half2_rn(b.x, b.y);
    p[3] = __floats2half2_rn(b.z, b.w);
    hh[i] = *reinterpret_cast<const uint4*>(p);
}

__device__ __forceinline__ float dot2u(unsigned a, unsigned b) {
    __half2 ha = *reinterpret_cast<const __half2*>(&a);
    __half2 hb = *reinterpret_cast<const __half2*>(&b);
    float2 fa = __half22float2(ha);
    float2 fb = __half22float2(hb);
    return fa.x * fb.x + fa.y * fb.y;
}

__device__ __forceinline__ float dot8u(uint4 a, uint4 b) {
    return dot2u(a.x, b.x) + dot2u(a.y, b.y) + dot2u(a.z, b.z) + dot2u(a.w, b.w);
}

__device__ __forceinline__ float dot16(const uint4* __restrict__ hh, int s, int d) {
    uint4 a0 = hh[(size_t)s * 2];
    uint4 a1 = hh[(size_t)s * 2 + 1];
    uint4 b0 = hh[(size_t)d * 2];
    uint4 b1 = hh[(size_t)d * 2 + 1];
    return dot8u(a0, b0) + dot8u(a1, b1);
}

// Phase 2: lane-pair per 8 edges/iter; 16 gathers (16B each) in flight per
// lane. Resident grid (<=2048 blocks) + grid-stride so warm threads pipeline
// across iterations instead of paying a cold latency chain per block.
__global__ __launch_bounds__(256) void edge_dot_pair8(
    const uint4* __restrict__ hh,    // [N*2] (row = 2 x uint4)
    const i32x4* __restrict__ src4,  // [E/4]
    const i32x4* __restrict__ dst4,  // [E/4]
    float4* __restrict__ out4,       // [E/4]
    int ng,                          // E/8
    const int* __restrict__ src,     // scalar views for tail
    const int* __restrict__ dst,
    float* __restrict__ out,
    int E)
{
    int tid = blockIdx.x * blockDim.x + threadIdx.x;
    int half = tid & 1;              // which 16B half of each 32B row
    int pair = tid >> 1;
    int pstride = (gridDim.x * blockDim.x) >> 1;

    for (int g = pair; g < ng; g += pstride) {
        i32x4 sA = src4[2 * g];
        i32x4 sB = src4[2 * g + 1];
        i32x4 dA = dst4[2 * g];
        i32x4 dB = dst4[2 * g + 1];
        int ss[8] = {sA.x, sA.y, sA.z, sA.w, sB.x, sB.y, sB.z, sB.w};
        int dd[8] = {dA.x, dA.y, dA.z, dA.w, dB.x, dB.y, dB.z, dB.w};
        uint4 av[8], bv[8];
#pragma unroll
        for (int k = 0; k < 8; ++k) av[k] = hh[(size_t)ss[k] * 2 + half];
#pragma unroll
        for (int k = 0; k < 8; ++k) bv[k] = hh[(size_t)dd[k] * 2 + half];
        float r[8];
#pragma unroll
        for (int k = 0; k < 8; ++k) {
            float partial = dot8u(av[k], bv[k]);
            r[k] = partial + __shfl_xor(partial, 1, 64);
        }
        // lane0 stores edges 0-3, lane1 stores edges 4-7: 32B contiguous/pair.
        float4 v;
        if (half == 0) { v.x = r[0]; v.y = r[1]; v.z = r[2]; v.w = r[3]; }
        else           { v.x = r[4]; v.y = r[5]; v.z = r[6]; v.w = r[7]; }
        out4[(size_t)g * 2 + half] = v;
    }

    // tail (E % 8 != 0)
    if (tid == 0) {
        for (int e = ng * 8; e < E; ++e)
            out[e] = dot16(hh, src[e], dst[e]);
    }
}

// Fallback (ws too small): fp32 gather kernel.
__global__ __launch_bounds__(256) void edge_dot_fp32(
    const float4* __restrict__ h,
    const int* __restrict__ src,
    const int* __restrict__ dst,
    float* __restrict__ out,
    int E)
{
    int idx = blockIdx.x * blockDim.x + threadIdx.x;
    int stride = gridDim.x * blockDim.x;
    for (int e = idx; e < E; e += stride) {
        int s = src[e];
        int d = dst[e];
        const float4* hs = h + (size_t)s * 4;
        const float4* hd = h + (size_t)d * 4;
        float acc = 0.0f;
#pragma unroll
        for (int k = 0; k < 4; ++k) {
            float4 a = hs[k];
            float4 b = hd[k];
            acc += a.x * b.x + a.y * b.y + a.z * b.z + a.w * b.w;
        }
        out[e] = acc;
    }
}

extern "C" void kernel_launch(void* const* d_in, const int* in_sizes, int n_in,
                              void* d_out, int out_size, void* d_ws, size_t ws_size,
                              hipStream_t stream) {
    const float* h   = (const float*)d_in[0];   // [N, 16] fp32
    const int*   src = (const int*)d_in[1];     // [E] int32
    const int*   dst = (const int*)d_in[2];     // [E]
    float*       out = (float*)d_out;           // [E]

    const int N = in_sizes[0] / 16;
    const int E = in_sizes[1];

    const size_t need = (size_t)N * 16 * sizeof(__half);  // 3.2 MB
    if (ws_size >= need && E >= 8) {
        uint4* hh = (uint4*)d_ws;
        int n_out = N * 2;
        convert_h_fp16<<<(n_out + 255) / 256, 256, 0, stream>>>(
            (const f32x4*)h, hh, n_out);

        int ng = E / 8;
        long long threads = (long long)ng * 2;
        int grid = (int)((threads + 255) / 256);
        if (grid > 2048) grid = 2048;   // resident grid; grid-stride covers rest
        if (grid < 1) grid = 1;
        edge_dot_pair8<<<grid, 256, 0, stream>>>(
            (const uint4*)hh, (const i32x4*)src, (const i32x4*)dst, (float4*)out,
            ng, src, dst, out, E);
    } else {
        int grid = (E + 255) / 256;
        if (grid > 2048) grid = 2048;
        edge_dot_fp32<<<grid, 256, 0, stream>>>(
            (const float4*)h, src, dst, out, E);
    }
}

// Round 10
// 41.388 us; speedup vs baseline: 1.5888x; 1.5888x over previous
//
#include <hip/hip_runtime.h>
#include <hip/hip_bf16.h>
#include <hip/hip_fp16.h>

// Phase 1: convert h (fp32, [N,16]) -> fp16 table in workspace (32 B/row).
// 3.2 MB fits per-XCD L2 (4 MB); fp32 table (6.4 MB) thrashed it (R1).
__global__ __launch_bounds__(256) void convert_h_fp16(
    const float4* __restrict__ h4,   // [N*4] float4
    uint4* __restrict__ hh,          // [N*2] uint4 (8 halfs each)
    int n_out)                       // N*2
{
    int i = blockIdx.x * blockDim.x + threadIdx.x;
    if (i >= n_out) return;
    float4 a = h4[2 * i];
    float4 b = h4[2 * i + 1];
    __half2 p[4];
    p[0] = __floats2half2_rn(a.x, a.y);
    p[1] = __floats2half2_rn(a.z, a.w);
    p[2] = __floats2half2_rn(b.x, b.y);
    p[3] = __floats2half2_rn(b.z, b.w);
    hh[i] = *reinterpret_cast<const uint4*>(p);
}

__device__ __forceinline__ float dot2u(unsigned a, unsigned b) {
    __half2 ha = *reinterpret_cast<const __half2*>(&a);
    __half2 hb = *reinterpret_cast<const __half2*>(&b);
    float2 fa = __half22float2(ha);
    float2 fb = __half22float2(hb);
    return fa.x * fb.x + fa.y * fb.y;
}

__device__ __forceinline__ float dot8u(uint4 a, uint4 b) {
    return dot2u(a.x, b.x) + dot2u(a.y, b.y) + dot2u(a.z, b.z) + dot2u(a.w, b.w);
}

__device__ __forceinline__ float dot16(const uint4* __restrict__ hh, int s, int d) {
    uint4 a0 = hh[(size_t)s * 2];
    uint4 a1 = hh[(size_t)s * 2 + 1];
    uint4 b0 = hh[(size_t)d * 2];
    uint4 b1 = hh[(size_t)d * 2 + 1];
    return dot8u(a0, b0) + dot8u(a1, b1);
}

// Phase 2: LANE-PAIR per edge group of 4 (R3 structure — proven best).
// Lanes 2i/2i+1 each own one 16B half of every 32B row (same 64B line ->
// one merged line-request per row). Immediate per-edge consumption keeps
// VGPR pressure low (R9's 8-deep register batching triggered an LDS
// demotion: VGPR=32, LDS=8192, 1M bank conflicts, +18us).
__global__ __launch_bounds__(256) void edge_dot_pair(
    const uint4* __restrict__ hh,    // [N*2] (row = 2 x uint4)
    const int4* __restrict__ src4,   // [E/4]
    const int4* __restrict__ dst4,   // [E/4]
    float2* __restrict__ out2,       // [E/2]
    int nq,                          // E/4
    const int* __restrict__ src,     // scalar views for tail
    const int* __restrict__ dst,
    float* __restrict__ out,
    int E)
{
    int tid = blockIdx.x * blockDim.x + threadIdx.x;
    int half = tid & 1;              // which 16B half of each row this lane owns
    int pair = tid >> 1;
    int pstride = (gridDim.x * blockDim.x) >> 1;

    for (int q = pair; q < nq; q += pstride) {
        int4 s4 = src4[q];           // broadcast within the pair
        int4 d4 = dst4[q];
        int ss[4] = {s4.x, s4.y, s4.z, s4.w};
        int dd[4] = {d4.x, d4.y, d4.z, d4.w};
        float r[4];
#pragma unroll
        for (int k = 0; k < 4; ++k) {
            uint4 a = hh[(size_t)ss[k] * 2 + half];
            uint4 b = hh[(size_t)dd[k] * 2 + half];
            float partial = dot8u(a, b);
            r[k] = partial + __shfl_xor(partial, 1, 64);
        }
        // Pair stores the 4 results as two adjacent float2 (16B coalesced).
        float2 v;
        v.x = half ? r[2] : r[0];
        v.y = half ? r[3] : r[1];
        out2[(size_t)q * 2 + half] = v;
    }

    // tail (E % 4 != 0)
    if (tid == 0) {
        for (int e = nq * 4; e < E; ++e)
            out[e] = dot16(hh, src[e], dst[e]);
    }
}

// Fallback (ws too small): fp32 gather kernel.
__global__ __launch_bounds__(256) void edge_dot_fp32(
    const float4* __restrict__ h,
    const int* __restrict__ src,
    const int* __restrict__ dst,
    float* __restrict__ out,
    int E)
{
    int idx = blockIdx.x * blockDim.x + threadIdx.x;
    int stride = gridDim.x * blockDim.x;
    for (int e = idx; e < E; e += stride) {
        int s = src[e];
        int d = dst[e];
        const float4* hs = h + (size_t)s * 4;
        const float4* hd = h + (size_t)d * 4;
        float acc = 0.0f;
#pragma unroll
        for (int k = 0; k < 4; ++k) {
            float4 a = hs[k];
            float4 b = hd[k];
            acc += a.x * b.x + a.y * b.y + a.z * b.z + a.w * b.w;
        }
        out[e] = acc;
    }
}

extern "C" void kernel_launch(void* const* d_in, const int* in_sizes, int n_in,
                              void* d_out, int out_size, void* d_ws, size_t ws_size,
                              hipStream_t stream) {
    const float* h   = (const float*)d_in[0];   // [N, 16] fp32
    const int*   src = (const int*)d_in[1];     // [E] int32
    const int*   dst = (const int*)d_in[2];     // [E]
    float*       out = (float*)d_out;           // [E]

    const int N = in_sizes[0] / 16;
    const int E = in_sizes[1];

    const size_t need = (size_t)N * 16 * sizeof(__half);  // 3.2 MB
    if (ws_size >= need && E >= 4) {
        uint4* hh = (uint4*)d_ws;
        int n_out = N * 2;
        convert_h_fp16<<<(n_out + 255) / 256, 256, 0, stream>>>(
            (const float4*)h, hh, n_out);

        int nq = E / 4;
        long long threads = (long long)nq * 2;
        int grid = (int)((threads + 255) / 256);
        if (grid < 1) grid = 1;
        edge_dot_pair<<<grid, 256, 0, stream>>>(
            (const uint4*)hh, (const int4*)src, (const int4*)dst, (float2*)out,
            nq, src, dst, out, E);
    } else {
        int grid = (E + 255) / 256;
        if (grid > 2048) grid = 2048;
        edge_dot_fp32<<<grid, 256, 0, stream>>>(
            (const float4*)h, src, dst, out, E);
    }
}